// Round 8
// baseline (6965.710 us; speedup 1.0000x reference)
//
#include <hip/hip_runtime.h>
#include <hip/hip_bf16.h>
#include <math.h>

typedef unsigned int uint32;
typedef _Float16 h2_t __attribute__((ext_vector_type(2)));

// Problem constants
static constexpr int NX = 32;    // state dim
static constexpr int NU = 8;     // control dim
static constexpr int NA = 24;    // obs dim
static constexpr int NH = 256;   // hidden
static constexpr int NT = 128;   // time steps
static constexpr int NB = 256;   // batch
static constexpr int NXP = 33;   // ODD padded row stride (bank-safe)
static constexpr float MINV = 0.01f, MAXV = 1.0f, EPSV = 1e-6f;

// Padded head widths (outputs)
static constexpr int H1O = NX*NX + NX*NU + NX;   // 1312 real
static constexpr int H1P = 1344;                 // padded
static constexpr int H2O = NA*NX + NA;           // 792 real
static constexpr int H2P = 800;                  // padded

// Workspace layout in uint32 units (all 16B aligned)
static constexpr size_t OFF_W1 = 0;
static constexpr size_t OFF_W2 = 4096;
static constexpr size_t OFF_H1 = OFF_W2 + 32768;
static constexpr size_t OFF_H2 = OFF_H1 + 172032;
static constexpr size_t OFF_B1 = OFF_H2 + 102400;
static constexpr size_t OFF_B2 = OFF_B1 + 1344;

// ---------------------------------------------------------------------------
__global__ void pack_half_off(const float* __restrict__ src, uint32* __restrict__ dst,
                              int O, int K, int LDP, int off)
{
    int idx = blockIdx.x * blockDim.x + threadIdx.x;
    int K2 = K >> 1;
    if (idx >= O * K2) return;
    int kk = idx % K2;
    int o  = idx / K2;
    int k  = kk * 2;
    int k8 = k >> 3, q = (k >> 1) & 3;
    _Float16 a = (_Float16)src[o * K + k];
    _Float16 b = (_Float16)src[o * K + k + 1];
    uint32 val = (uint32)__builtin_bit_cast(unsigned short, a)
               | ((uint32)__builtin_bit_cast(unsigned short, b) << 16);
    dst[((size_t)k8 * LDP + off + o) * 4 + q] = val;
}

__global__ void pack_bias3(const float* __restrict__ s0, int n0,
                           const float* __restrict__ s1, int n1,
                           const float* __restrict__ s2, int n2,
                           float* __restrict__ dst)
{
    int i = blockIdx.x * blockDim.x + threadIdx.x;
    if (i < n0) dst[i] = s0[i];
    else if (i < n0 + n1) dst[i] = s1[i - n0];
    else if (i < n0 + n1 + n2) dst[i] = s2[i - n0 - n1];
}

// ---------------------------------------------------------------------------
__device__ __forceinline__ float dot2(uint32 w, uint32 x, float acc)
{
#if __has_builtin(__builtin_amdgcn_fdot2)
    return __builtin_amdgcn_fdot2(__builtin_bit_cast(h2_t, w),
                                  __builtin_bit_cast(h2_t, x), acc, false);
#else
    h2_t a = __builtin_bit_cast(h2_t, w), b = __builtin_bit_cast(h2_t, x);
    return acc + (float)a[0] * (float)b[0] + (float)a[1] * (float)b[1];
#endif
}

__device__ __forceinline__ float dot8(uint4 w, uint4 x, float acc)
{
    acc = dot2(w.x, x.x, acc);
    acc = dot2(w.y, x.y, acc);
    acc = dot2(w.z, x.z, acc);
    acc = dot2(w.w, x.w, acc);
    return acc;
}

__device__ __forceinline__ void tri_decode(int p, int& l, int& i)
{
    int lo = (int)((sqrtf(8.f * (float)p + 1.f) - 1.f) * 0.5f);
    while ((lo + 1) * (lo + 2) / 2 <= p) lo++;
    while (lo * (lo + 1) / 2 > p) lo--;
    l = lo;
    i = p - lo * (lo + 1) / 2;
}

__device__ __forceinline__ float sigm_scaled(float z)
{
    return MINV + (MAXV - MINV) / (1.f + expf(-z));
}

__device__ __forceinline__ unsigned short f2h(float v)
{
    _Float16 h = (_Float16)v;
    return __builtin_bit_cast(unsigned short, h);
}

__device__ __forceinline__ void pack1_to(int tid, float v, uint32* d)
{
    unsigned short us = f2h(v);
    int pi = __shfl_xor((int)us, 1);
    if ((tid & 1) == 0)
        d[tid >> 1] = (uint32)us | ((uint32)pi << 16);
}

// Padded h1 writer: logical uint4 index g*8+kk maps to physical g*9+kk
// (one uint4 gap per 64-element split-K group). The trunk's quad read then
// hits banks {4g+4kk..} all distinct -> conflict-free. Counter-verified:
// SQ_LDS_BANK_CONFLICT 39.4M (R2) -> 5.98M (R7), dur -34us.
__device__ __forceinline__ void pack1_h1(int tid, float v, uint32* d)
{
    unsigned short us = f2h(v);
    int pi = __shfl_xor((int)us, 1);
    if ((tid & 1) == 0)
        d[(tid >> 1) + ((tid >> 6) << 2)] = (uint32)us | ((uint32)pi << 16);
}

// LDS-only fence + block barrier (no vmcnt drain). Stores live only in
// phases without latency-critical global loads; one vmcnt(0) per step (P10)
// bounds store-queue buildup.
__device__ __forceinline__ void bar()
{
    asm volatile("s_waitcnt lgkmcnt(0)" ::: "memory");
    __builtin_amdgcn_s_barrier();
    asm volatile("" ::: "memory");
}

// ---------------------------------------------------------------------------
// 1 batch element per block, 1024 threads, 1 block/CU. 10 barriers/step.
// NOTE (R4/R5 lesson): do NOT add per-lane register arrays (e.g. weight
// prefetch buffers) — the allocator pins VGPR=64 and spills to scratch
// (FETCH_SIZE 16MB -> 3.5-4.5GB, +70-90% dur). Only LDS-destination or
// layout changes are safe on this kernel.
// R8 change (single variable): P3 head1 tail split — all lanes carry one Am
// output (32 loads); the 288 tail outputs run split-K x2 on lanes 448-1023
// (16 loads each, const bounds). Max per-lane loads 64 -> 48, bytes equal.
__global__ __launch_bounds__(1024, 4) void kf_kernel(
    const float* __restrict__ u, const float* __restrict__ a,
    const uint32* __restrict__ wsu,
    const float* __restrict__ b1, const float* __restrict__ b2,
    const float* __restrict__ alpha_p,
    float* __restrict__ out)
{
    const int tid = threadIdx.x;
    const int b   = blockIdx.x;
    const float alpha = alpha_p[0];

    const uint4* W1h = (const uint4*)(wsu + OFF_W1);
    const uint4* W2h = (const uint4*)(wsu + OFF_W2);
    const uint4* H1h = (const uint4*)(wsu + OFF_H1);
    const uint4* H2h = (const uint4*)(wsu + OFF_H2);
    const float* BH1 = (const float*)(wsu + OFF_B1);
    const float* BH2 = (const float*)(wsu + OFF_B2);

    // W2 resident in LDS: s_w2[kk*1024 + tid]; wave reads are 1KB contiguous.
    __shared__ alignas(16) uint4 s_w2[8 * 1024];          // 131072 B

    __shared__ alignas(16) uint32 s_h1h[144];             // padded (9 uint4 / group)
    __shared__ alignas(16) uint32 s_h2h[NH / 2];
    __shared__ alignas(16) uint32 s_qmh[NX / 2];
    __shared__ alignas(16) uint32 s_pmh[NX / 2];
    __shared__ alignas(16) float s_Am[NX * NXP];
    __shared__ float s_Bm[NX * NU];
    __shared__ float s_nx[NX];
    __shared__ alignas(16) float s_C[NA * NXP];
    __shared__ float s_na[NA];
    __shared__ float s_qm[NX];
    __shared__ alignas(16) float s_qc[NX * NXP];
    __shared__ float s_pm[NX];
    __shared__ alignas(16) float s_pc[NX * NXP];
    __shared__ alignas(16) float s_T2[NX * NXP];
    __shared__ alignas(16) float s_T1[NA * NXP];
    __shared__ float s_S[NA * NA];
    __shared__ float s_Y[NA * NX];
    __shared__ float s_innov[NA];
    __shared__ float s_a[NA], s_u[NU];

    const size_t pmO = 0;
    const size_t pcO = (size_t)NT * NB * NX;
    const size_t qmO = pcO + (size_t)NT * NB * NX * NX;
    const size_t qcO = qmO + (size_t)NT * NB * NX;

    // One-time: stage W2 into LDS in the wave-contiguous layout.
    {
        const int o = tid >> 2, g = tid & 3;
        #pragma unroll
        for (int kk = 0; kk < 8; kk++)
            s_w2[kk * 1024 + tid] = W2h[(g * 8 + kk) * NH + o];
    }

    // Hoisted per-lane constants (invariant over t)
    const float b1v  = (tid < NH) ? b1[tid] : 0.f;
    const float b2v  = b2[tid >> 2];
    const float bh1a = BH1[tid];
    const float bh1t = (tid >= 448) ? BH1[1024 + ((tid - 448) >> 1)] : 0.f;
    const float bh2v = (tid < H2P) ? BH2[tid] : 0.f;

    // Hoisted triangular index maps (constant over t)
    int iT = 0, lT = 0;                 // 528-item 32x32 triangle on lanes 256-783
    if (tid >= 256 && tid < 784) tri_decode(tid - 256, lT, iT);
    int iS = 0, lS = 0;                 // 300-item 24x24 triangle, tid<300
    if (tid < 300) tri_decode(tid, lS, iS);

    for (int t = 0; t < NT; ++t) {
        const size_t mIdx = (size_t)t * NB + b;

        if (t == 0) {
            if (tid < NX) s_pm[tid] = 0.f;
            if (tid < NX / 2) s_pmh[tid] = 0u;
            {
                int i = tid >> 5, l = tid & 31;
                s_pc[i * NXP + l] = (i == l) ? 1.f : 0.f;
            }
            bar();   // also covers the s_w2 staging above
        } else {
            const size_t mPrev = (size_t)(t - 1) * NB + b;

            // ===== P1: W1@qm || qc-psd (prev Y,T1,pc) || qm store || u load =====
            if (tid < NH) {
                const uint4* xh = (const uint4*)s_qmh;
                float acc = b1v;
                #pragma unroll
                for (int k8 = 0; k8 < 4; k8++)
                    acc = dot8(W1h[k8 * NH + tid], xh[k8], acc);
                pack1_h1(tid, fmaxf(acc, 0.f), s_h1h);
            } else if (tid < 784) {
                const int i = iT, l = lT;
                float t_il = 0.f, t_li = 0.f;
                #pragma unroll
                for (int q = 0; q < NA; q++) {
                    t_il = fmaf(s_Y[q * NX + i], s_T1[q * NXP + l], t_il);
                    t_li = fmaf(s_Y[q * NX + l], s_T1[q * NXP + i], t_li);
                }
                if (i == l) {
                    s_qc[i * NXP + i] = s_pc[i * NXP + i] - t_il + EPSV;
                } else {
                    float v = 0.5f * ((s_pc[i * NXP + l] - t_il) + (s_pc[l * NXP + i] - t_li));
                    s_qc[i * NXP + l] = v;
                    s_qc[l * NXP + i] = v;
                }
            } else if (tid < 816) {
                __builtin_nontemporal_store(s_qm[tid - 784], out + qmO + mPrev * NX + (tid - 784));
            } else if (tid < 824) {
                s_u[tid - 816] = u[mPrev * NU + (tid - 816)];
            }
            bar();

            // ===== P2: trunk (W2 from LDS, quad split-K) || qc store =====
            {
                __builtin_nontemporal_store(s_qc[(tid >> 5) * NXP + (tid & 31)],
                                            out + qcO + mPrev * (NX * NX) + tid);
                const uint4* xh = (const uint4*)s_h1h;
                float acc = 0.f;
                #pragma unroll
                for (int kk = 0; kk < 8; kk++)
                    acc = dot8(s_w2[kk * 1024 + tid], xh[(tid & 3) * 9 + kk], acc);
                acc += __shfl_xor(acc, 1);
                acc += __shfl_xor(acc, 2);
                float v = fmaxf(acc + b2v, 0.f);
                unsigned short us = f2h(v);
                int pi = __shfl_xor((int)us, 4);
                if ((tid & 7) == 0) s_h2h[tid >> 3] = (uint32)us | ((uint32)pi << 16);
            }
            bar();

            // ===== P3: head1 — all lanes Am (32 loads); tail 288 outputs
            //       split-K x2 on lanes 448-1023 (16 loads, const bounds) =====
            {
                const uint4* xh = (const uint4*)s_h2h;
                float a0 = bh1a;
                #pragma unroll 8
                for (int k8 = 0; k8 < 32; k8++)
                    a0 = dot8(H1h[k8 * H1P + tid], xh[k8], a0);
                {
                    int i = tid >> 5, l = tid & 31;
                    s_Am[i * NXP + l] = ((i == l) ? 1.f : 0.f) + alpha * a0;
                }
                if (tid >= 448) {
                    int tau = tid - 448;
                    int o1 = 1024 + (tau >> 1);
                    float a1;
                    if ((tau & 1) == 0) {
                        a1 = bh1t;
                        #pragma unroll
                        for (int k8 = 0; k8 < 16; k8++)
                            a1 = dot8(H1h[k8 * H1P + o1], xh[k8], a1);
                    } else {
                        a1 = 0.f;
                        #pragma unroll
                        for (int k8 = 16; k8 < 32; k8++)
                            a1 = dot8(H1h[k8 * H1P + o1], xh[k8], a1);
                    }
                    float a1tot = a1 + __shfl_xor(a1, 1);
                    if ((tau & 1) == 0) {
                        if (o1 < NX * NX + NX * NU) s_Bm[o1 - NX * NX] = a1tot;
                        else s_nx[o1 - (NX * NX + NX * NU)] = sigm_scaled(a1tot);
                    }
                }
            }
            bar();

            // ===== P4: T2 = Am@qc || pm = Am@qm + Bm@u =====
            {
                int i = tid >> 5, l = tid & 31;
                float acc = 0.f;
                #pragma unroll
                for (int j = 0; j < NX; j++)
                    acc = fmaf(s_Am[i * NXP + j], s_qc[j * NXP + l], acc);
                s_T2[i * NXP + l] = acc;
            }
            if (tid < NX) {
                float acc = 0.f;
                #pragma unroll
                for (int j = 0; j < NX; j++) acc = fmaf(s_Am[tid * NXP + j], s_qm[j], acc);
                #pragma unroll
                for (int j = 0; j < NU; j++) acc = fmaf(s_Bm[tid * NU + j], s_u[j], acc);
                s_pm[tid] = acc;
                pack1_to(tid, acc, s_pmh);
            }
            bar();
        }

        // ===== P5: W1@pm || pc = psd(T2 Am^T + nx) || pm store || a load =====
        if (tid < NH) {
            const uint4* xh = (const uint4*)s_pmh;
            float acc = b1v;
            #pragma unroll
            for (int k8 = 0; k8 < 4; k8++)
                acc = dot8(W1h[k8 * NH + tid], xh[k8], acc);
            pack1_h1(tid, fmaxf(acc, 0.f), s_h1h);
        } else if (tid < 784) {
            if (t > 0) {
                const int i = iT, l = lT;
                float a_il = 0.f, a_li = 0.f;
                #pragma unroll
                for (int j = 0; j < NX; j++) {
                    a_il = fmaf(s_T2[i * NXP + j], s_Am[l * NXP + j], a_il);
                    a_li = fmaf(s_T2[l * NXP + j], s_Am[i * NXP + j], a_li);
                }
                if (i == l) {
                    s_pc[i * NXP + i] = a_il + s_nx[i] + EPSV;
                } else {
                    float v = 0.5f * (a_il + a_li);
                    s_pc[i * NXP + l] = v;
                    s_pc[l * NXP + i] = v;
                }
            }
        } else if (tid < 816) {
            __builtin_nontemporal_store(s_pm[tid - 784], out + pmO + mIdx * NX + (tid - 784));
        } else if (tid < 840) {
            s_a[tid - 816] = a[mIdx * NA + (tid - 816)];
        }
        bar();

        // ===== P6: trunk (W2 from LDS) || pc store =====
        {
            __builtin_nontemporal_store(s_pc[(tid >> 5) * NXP + (tid & 31)],
                                        out + pcO + mIdx * (NX * NX) + tid);
            const uint4* xh = (const uint4*)s_h1h;
            float acc = 0.f;
            #pragma unroll
            for (int kk = 0; kk < 8; kk++)
                acc = dot8(s_w2[kk * 1024 + tid], xh[(tid & 3) * 9 + kk], acc);
            acc += __shfl_xor(acc, 1);
            acc += __shfl_xor(acc, 2);
            float v = fmaxf(acc + b2v, 0.f);
            unsigned short us = f2h(v);
            int pi = __shfl_xor((int)us, 4);
            if ((tid & 7) == 0) s_h2h[tid >> 3] = (uint32)us | ((uint32)pi << 16);
        }
        bar();

        // ===== P7: head2 (C | na) — pure load/compute phase =====
        if (tid < H2P) {
            const uint4* xh = (const uint4*)s_h2h;
            float acc = bh2v;
            #pragma unroll 8
            for (int k8 = 0; k8 < 32; k8++)
                acc = dot8(H2h[k8 * H2P + tid], xh[k8], acc);
            if (tid < NA * NX) {
                int i = tid >> 5, l = tid & 31;
                s_C[i * NXP + l] = acc;
            } else if (tid < H2O) {
                s_na[tid - NA * NX] = sigm_scaled(acc);
            }
        }
        bar();

        // ===== P8: T1 = C@pc || innov = a - C@pm =====
        if (tid < NA * NX) {
            int i = tid >> 5, l = tid & 31;
            float acc = 0.f;
            #pragma unroll
            for (int k = 0; k < NX; k++)
                acc = fmaf(s_C[i * NXP + k], s_pc[k * NXP + l], acc);
            s_T1[i * NXP + l] = acc;
        } else if (tid < NA * NX + NA) {
            int i = tid - NA * NX;
            float acc = s_a[i];
            #pragma unroll
            for (int j = 0; j < NX; j++)
                acc = fmaf(-s_C[i * NXP + j], s_pm[j], acc);
            s_innov[i] = acc;
        }
        bar();

        // ===== P9: S = T1 @ C^T + diag(na) =====
        if (tid < 300) {
            float acc = 0.f;
            #pragma unroll
            for (int j = 0; j < NX; j++)
                acc = fmaf(s_T1[iS * NXP + j], s_C[lS * NXP + j], acc);
            if (iS == lS) acc += s_na[iS];
            s_S[iS * NA + lS] = acc;
            s_S[lS * NA + iS] = acc;
        }
        bar();

        // ===== P10: single-wave Gauss-Jordan: Y = S^-1 T1, qm folded in =====
        if (tid < 64) {
            const int j = tid;
            float r[NA];
            #pragma unroll
            for (int i = 0; i < NA; i++) {
                float v = 0.f;
                if (j < NA) v = s_S[i * NA + j];
                else if (j < NA + NX) v = s_T1[i * NXP + (j - NA)];
                r[i] = v;
            }
            #pragma unroll
            for (int k = 0; k < NA; k++) {
                float piv = __shfl(r[k], k);
                float ip = 1.0f / piv;
                r[k] *= ip;
                #pragma unroll
                for (int i = 0; i < NA; i++) {
                    if (i == k) continue;
                    float f = __shfl(r[i], k);
                    r[i] = fmaf(-f, r[k], r[i]);
                }
            }
            if (j >= NA && j < NA + NX) {
                const int x = j - NA;
                float acc = s_pm[x];
                #pragma unroll
                for (int i = 0; i < NA; i++) {
                    s_Y[i * NX + x] = r[i];
                    acc = fmaf(r[i], s_innov[i], acc);
                }
                s_qm[x] = acc;
                unsigned short us = f2h(acc);
                int pi = __shfl_xor((int)us, 1);
                if ((x & 1) == 0) s_qmh[x >> 1] = (uint32)us | ((uint32)pi << 16);
            }
        }
        // Per-step store-queue drain on otherwise-idle waves.
        asm volatile("s_waitcnt vmcnt(0)" ::: "memory");
        bar();
    }

    // Epilogue: qc for t = NT-1, then store qm/qc (coalesced)
    if (tid >= 256 && tid < 784) {
        const int i = iT, l = lT;
        float t_il = 0.f, t_li = 0.f;
        #pragma unroll
        for (int q = 0; q < NA; q++) {
            t_il = fmaf(s_Y[q * NX + i], s_T1[q * NXP + l], t_il);
            t_li = fmaf(s_Y[q * NX + l], s_T1[q * NXP + i], t_li);
        }
        if (i == l) {
            s_qc[i * NXP + i] = s_pc[i * NXP + i] - t_il + EPSV;
        } else {
            float v = 0.5f * ((s_pc[i * NXP + l] - t_il) + (s_pc[l * NXP + i] - t_li));
            s_qc[i * NXP + l] = v;
            s_qc[l * NXP + i] = v;
        }
    }
    bar();
    {
        const size_t mLast = (size_t)(NT - 1) * NB + b;
        for (int s = tid; s < NX + NX * NX; s += 1024) {
            if (s < NX)
                __builtin_nontemporal_store(s_qm[s], out + qmO + mLast * NX + s);
            else {
                int o = s - NX, i = o >> 5, l = o & 31;
                __builtin_nontemporal_store(s_qc[i * NXP + l],
                                            out + qcO + mLast * NX * NX + o);
            }
        }
    }
}

// ---------------------------------------------------------------------------
extern "C" void kernel_launch(void* const* d_in, const int* in_sizes, int n_in,
                              void* d_out, int out_size, void* d_ws, size_t ws_size,
                              hipStream_t stream)
{
    const float* u    = (const float*)d_in[0];
    const float* a    = (const float*)d_in[1];
    const float* W1   = (const float*)d_in[2];
    const float* b1   = (const float*)d_in[3];
    const float* W2   = (const float*)d_in[4];
    const float* b2   = (const float*)d_in[5];
    const float* WA   = (const float*)d_in[6];
    const float* bA   = (const float*)d_in[7];
    const float* WB   = (const float*)d_in[8];
    const float* bB   = (const float*)d_in[9];
    const float* WC   = (const float*)d_in[10];
    const float* bC   = (const float*)d_in[11];
    const float* Wnx  = (const float*)d_in[12];
    const float* bnx  = (const float*)d_in[13];
    const float* Wna  = (const float*)d_in[14];
    const float* bna  = (const float*)d_in[15];
    const float* alph = (const float*)d_in[16];

    uint32* wsu = (uint32*)d_ws;
    float* out = (float*)d_out;

    auto pk = [&](const float* src, int O, int K, size_t dst_off, int LDP, int off) {
        int n = O * (K / 2);
        pack_half_off<<<(n + 255) / 256, 256, 0, stream>>>(src, wsu + dst_off, O, K, LDP, off);
    };
    pk(W1,  NH,      NX, OFF_W1, NH,  0);
    pk(W2,  NH,      NH, OFF_W2, NH,  0);
    pk(WA,  NX * NX, NH, OFF_H1, H1P, 0);
    pk(WB,  NX * NU, NH, OFF_H1, H1P, NX * NX);
    pk(Wnx, NX,      NH, OFF_H1, H1P, NX * NX + NX * NU);
    pk(WC,  NA * NX, NH, OFF_H2, H2P, 0);
    pk(Wna, NA,      NH, OFF_H2, H2P, NA * NX);

    pack_bias3<<<(H1O + 255) / 256, 256, 0, stream>>>(bA, NX * NX, bB, NX * NU, bnx, NX,
                                                      (float*)(wsu + OFF_B1));
    pack_bias3<<<(H2O + 255) / 256, 256, 0, stream>>>(bC, NA * NX, bna, NA, nullptr, 0,
                                                      (float*)(wsu + OFF_B2));

    kf_kernel<<<NB, 1024, 0, stream>>>(u, a, wsu, b1, b2, alph, out);
}

// Round 9
// 3981.041 us; speedup vs baseline: 1.7497x; 1.7497x over previous
//
#include <hip/hip_runtime.h>
#include <hip/hip_bf16.h>
#include <math.h>

typedef unsigned int uint32;
typedef _Float16 h2_t __attribute__((ext_vector_type(2)));

// Problem constants
static constexpr int NX = 32;    // state dim
static constexpr int NU = 8;     // control dim
static constexpr int NA = 24;    // obs dim
static constexpr int NH = 256;   // hidden
static constexpr int NT = 128;   // time steps
static constexpr int NB = 256;   // batch
static constexpr int NXP = 33;   // ODD padded row stride (bank-safe)
static constexpr float MINV = 0.01f, MAXV = 1.0f, EPSV = 1e-6f;

// Padded head widths (outputs)
static constexpr int H1O = NX*NX + NX*NU + NX;   // 1312 real
static constexpr int H1P = 1344;                 // padded
static constexpr int H2O = NA*NX + NA;           // 792 real
static constexpr int H2P = 800;                  // padded

// Workspace layout in uint32 units (all 16B aligned)
static constexpr size_t OFF_W1 = 0;
static constexpr size_t OFF_W2 = 4096;
static constexpr size_t OFF_H1 = OFF_W2 + 32768;
static constexpr size_t OFF_H2 = OFF_H1 + 172032;
static constexpr size_t OFF_B1 = OFF_H2 + 102400;
static constexpr size_t OFF_B2 = OFF_B1 + 1344;

// ---------------------------------------------------------------------------
__global__ void pack_half_off(const float* __restrict__ src, uint32* __restrict__ dst,
                              int O, int K, int LDP, int off)
{
    int idx = blockIdx.x * blockDim.x + threadIdx.x;
    int K2 = K >> 1;
    if (idx >= O * K2) return;
    int kk = idx % K2;
    int o  = idx / K2;
    int k  = kk * 2;
    int k8 = k >> 3, q = (k >> 1) & 3;
    _Float16 a = (_Float16)src[o * K + k];
    _Float16 b = (_Float16)src[o * K + k + 1];
    uint32 val = (uint32)__builtin_bit_cast(unsigned short, a)
               | ((uint32)__builtin_bit_cast(unsigned short, b) << 16);
    dst[((size_t)k8 * LDP + off + o) * 4 + q] = val;
}

__global__ void pack_bias3(const float* __restrict__ s0, int n0,
                           const float* __restrict__ s1, int n1,
                           const float* __restrict__ s2, int n2,
                           float* __restrict__ dst)
{
    int i = blockIdx.x * blockDim.x + threadIdx.x;
    if (i < n0) dst[i] = s0[i];
    else if (i < n0 + n1) dst[i] = s1[i - n0];
    else if (i < n0 + n1 + n2) dst[i] = s2[i - n0 - n1];
}

// ---------------------------------------------------------------------------
__device__ __forceinline__ float dot2(uint32 w, uint32 x, float acc)
{
#if __has_builtin(__builtin_amdgcn_fdot2)
    return __builtin_amdgcn_fdot2(__builtin_bit_cast(h2_t, w),
                                  __builtin_bit_cast(h2_t, x), acc, false);
#else
    h2_t a = __builtin_bit_cast(h2_t, w), b = __builtin_bit_cast(h2_t, x);
    return acc + (float)a[0] * (float)b[0] + (float)a[1] * (float)b[1];
#endif
}

__device__ __forceinline__ float dot8(uint4 w, uint4 x, float acc)
{
    acc = dot2(w.x, x.x, acc);
    acc = dot2(w.y, x.y, acc);
    acc = dot2(w.z, x.z, acc);
    acc = dot2(w.w, x.w, acc);
    return acc;
}

__device__ __forceinline__ void tri_decode(int p, int& l, int& i)
{
    int lo = (int)((sqrtf(8.f * (float)p + 1.f) - 1.f) * 0.5f);
    while ((lo + 1) * (lo + 2) / 2 <= p) lo++;
    while (lo * (lo + 1) / 2 > p) lo--;
    l = lo;
    i = p - lo * (lo + 1) / 2;
}

__device__ __forceinline__ float sigm_scaled(float z)
{
    return MINV + (MAXV - MINV) / (1.f + expf(-z));
}

__device__ __forceinline__ unsigned short f2h(float v)
{
    _Float16 h = (_Float16)v;
    return __builtin_bit_cast(unsigned short, h);
}

__device__ __forceinline__ void pack1_to(int tid, float v, uint32* d)
{
    unsigned short us = f2h(v);
    int pi = __shfl_xor((int)us, 1);
    if ((tid & 1) == 0)
        d[tid >> 1] = (uint32)us | ((uint32)pi << 16);
}

// Padded h1 writer: logical uint4 index g*8+kk maps to physical g*9+kk
// (one uint4 gap per 64-element split-K group). The trunk's quad read then
// hits banks {4g+4kk..} all distinct -> conflict-free. Counter-verified:
// SQ_LDS_BANK_CONFLICT 39.4M (R2) -> 5.98M (R7), dur -34us.
__device__ __forceinline__ void pack1_h1(int tid, float v, uint32* d)
{
    unsigned short us = f2h(v);
    int pi = __shfl_xor((int)us, 1);
    if ((tid & 1) == 0)
        d[(tid >> 1) + ((tid >> 6) << 2)] = (uint32)us | ((uint32)pi << 16);
}

// LDS-only fence + block barrier (no vmcnt drain). Stores live only in
// phases without latency-critical global loads; one vmcnt(0) per step (P10)
// bounds store-queue buildup.
__device__ __forceinline__ void bar()
{
    asm volatile("s_waitcnt lgkmcnt(0)" ::: "memory");
    __builtin_amdgcn_s_barrier();
    asm volatile("" ::: "memory");
}

// ---------------------------------------------------------------------------
// 1 batch element per block, 1024 threads, 1 block/CU. 10 barriers/step.
// SPILL RULE (R4/R5/R8 lesson, FETCH 16MB -> 3.5-4.5GB signature): any
// compile-time-constant batch of >= ~12 uint4 global loads that the compiler
// can hoist as a group (register prefetch arrays, fully-unrolled 16-load
// loops) spills to scratch at the pinned VGPR=64 allocation. Streamed loops
// with partial unroll <= 8 are safe (R2/R7 main loops, R3 tail).
// R9 change (single variable vs R7): P3 tail split with #pragma unroll 4 —
// max per-lane loads 64 -> 48, in-flight load batch capped at 4 uint4.
__global__ __launch_bounds__(1024, 4) void kf_kernel(
    const float* __restrict__ u, const float* __restrict__ a,
    const uint32* __restrict__ wsu,
    const float* __restrict__ b1, const float* __restrict__ b2,
    const float* __restrict__ alpha_p,
    float* __restrict__ out)
{
    const int tid = threadIdx.x;
    const int b   = blockIdx.x;
    const float alpha = alpha_p[0];

    const uint4* W1h = (const uint4*)(wsu + OFF_W1);
    const uint4* W2h = (const uint4*)(wsu + OFF_W2);
    const uint4* H1h = (const uint4*)(wsu + OFF_H1);
    const uint4* H2h = (const uint4*)(wsu + OFF_H2);
    const float* BH1 = (const float*)(wsu + OFF_B1);
    const float* BH2 = (const float*)(wsu + OFF_B2);

    // W2 resident in LDS: s_w2[kk*1024 + tid]; wave reads are 1KB contiguous.
    __shared__ alignas(16) uint4 s_w2[8 * 1024];          // 131072 B

    __shared__ alignas(16) uint32 s_h1h[144];             // padded (9 uint4 / group)
    __shared__ alignas(16) uint32 s_h2h[NH / 2];
    __shared__ alignas(16) uint32 s_qmh[NX / 2];
    __shared__ alignas(16) uint32 s_pmh[NX / 2];
    __shared__ alignas(16) float s_Am[NX * NXP];
    __shared__ float s_Bm[NX * NU];
    __shared__ float s_nx[NX];
    __shared__ alignas(16) float s_C[NA * NXP];
    __shared__ float s_na[NA];
    __shared__ float s_qm[NX];
    __shared__ alignas(16) float s_qc[NX * NXP];
    __shared__ float s_pm[NX];
    __shared__ alignas(16) float s_pc[NX * NXP];
    __shared__ alignas(16) float s_T2[NX * NXP];
    __shared__ alignas(16) float s_T1[NA * NXP];
    __shared__ float s_S[NA * NA];
    __shared__ float s_Y[NA * NX];
    __shared__ float s_innov[NA];
    __shared__ float s_a[NA], s_u[NU];

    const size_t pmO = 0;
    const size_t pcO = (size_t)NT * NB * NX;
    const size_t qmO = pcO + (size_t)NT * NB * NX * NX;
    const size_t qcO = qmO + (size_t)NT * NB * NX;

    // One-time: stage W2 into LDS in the wave-contiguous layout.
    {
        const int o = tid >> 2, g = tid & 3;
        #pragma unroll
        for (int kk = 0; kk < 8; kk++)
            s_w2[kk * 1024 + tid] = W2h[(g * 8 + kk) * NH + o];
    }

    // Hoisted per-lane constants (invariant over t)
    const float b1v  = (tid < NH) ? b1[tid] : 0.f;
    const float b2v  = b2[tid >> 2];
    const float bh1a = BH1[tid];
    const float bh1t = (tid >= 448) ? BH1[1024 + ((tid - 448) >> 1)] : 0.f;
    const float bh2v = (tid < H2P) ? BH2[tid] : 0.f;

    // Hoisted triangular index maps (constant over t)
    int iT = 0, lT = 0;                 // 528-item 32x32 triangle on lanes 256-783
    if (tid >= 256 && tid < 784) tri_decode(tid - 256, lT, iT);
    int iS = 0, lS = 0;                 // 300-item 24x24 triangle, tid<300
    if (tid < 300) tri_decode(tid, lS, iS);

    for (int t = 0; t < NT; ++t) {
        const size_t mIdx = (size_t)t * NB + b;

        if (t == 0) {
            if (tid < NX) s_pm[tid] = 0.f;
            if (tid < NX / 2) s_pmh[tid] = 0u;
            {
                int i = tid >> 5, l = tid & 31;
                s_pc[i * NXP + l] = (i == l) ? 1.f : 0.f;
            }
            bar();   // also covers the s_w2 staging above
        } else {
            const size_t mPrev = (size_t)(t - 1) * NB + b;

            // ===== P1: W1@qm || qc-psd (prev Y,T1,pc) || qm store || u load =====
            if (tid < NH) {
                const uint4* xh = (const uint4*)s_qmh;
                float acc = b1v;
                #pragma unroll
                for (int k8 = 0; k8 < 4; k8++)
                    acc = dot8(W1h[k8 * NH + tid], xh[k8], acc);
                pack1_h1(tid, fmaxf(acc, 0.f), s_h1h);
            } else if (tid < 784) {
                const int i = iT, l = lT;
                float t_il = 0.f, t_li = 0.f;
                #pragma unroll
                for (int q = 0; q < NA; q++) {
                    t_il = fmaf(s_Y[q * NX + i], s_T1[q * NXP + l], t_il);
                    t_li = fmaf(s_Y[q * NX + l], s_T1[q * NXP + i], t_li);
                }
                if (i == l) {
                    s_qc[i * NXP + i] = s_pc[i * NXP + i] - t_il + EPSV;
                } else {
                    float v = 0.5f * ((s_pc[i * NXP + l] - t_il) + (s_pc[l * NXP + i] - t_li));
                    s_qc[i * NXP + l] = v;
                    s_qc[l * NXP + i] = v;
                }
            } else if (tid < 816) {
                __builtin_nontemporal_store(s_qm[tid - 784], out + qmO + mPrev * NX + (tid - 784));
            } else if (tid < 824) {
                s_u[tid - 816] = u[mPrev * NU + (tid - 816)];
            }
            bar();

            // ===== P2: trunk (W2 from LDS, quad split-K) || qc store =====
            {
                __builtin_nontemporal_store(s_qc[(tid >> 5) * NXP + (tid & 31)],
                                            out + qcO + mPrev * (NX * NX) + tid);
                const uint4* xh = (const uint4*)s_h1h;
                float acc = 0.f;
                #pragma unroll
                for (int kk = 0; kk < 8; kk++)
                    acc = dot8(s_w2[kk * 1024 + tid], xh[(tid & 3) * 9 + kk], acc);
                acc += __shfl_xor(acc, 1);
                acc += __shfl_xor(acc, 2);
                float v = fmaxf(acc + b2v, 0.f);
                unsigned short us = f2h(v);
                int pi = __shfl_xor((int)us, 4);
                if ((tid & 7) == 0) s_h2h[tid >> 3] = (uint32)us | ((uint32)pi << 16);
            }
            bar();

            // ===== P3: head1 — all lanes Am (32 loads, unroll 8); tail 288
            //       outputs split-K x2 on lanes 448-1023 (16 loads each,
            //       UNROLL 4 to cap the hoistable load batch — spill rule) =====
            {
                const uint4* xh = (const uint4*)s_h2h;
                float a0 = bh1a;
                #pragma unroll 8
                for (int k8 = 0; k8 < 32; k8++)
                    a0 = dot8(H1h[k8 * H1P + tid], xh[k8], a0);
                {
                    int i = tid >> 5, l = tid & 31;
                    s_Am[i * NXP + l] = ((i == l) ? 1.f : 0.f) + alpha * a0;
                }
                if (tid >= 448) {
                    int tau = tid - 448;
                    int o1 = 1024 + (tau >> 1);
                    float a1;
                    if ((tau & 1) == 0) {
                        a1 = bh1t;
                        #pragma unroll 4
                        for (int k8 = 0; k8 < 16; k8++)
                            a1 = dot8(H1h[k8 * H1P + o1], xh[k8], a1);
                    } else {
                        a1 = 0.f;
                        #pragma unroll 4
                        for (int k8 = 16; k8 < 32; k8++)
                            a1 = dot8(H1h[k8 * H1P + o1], xh[k8], a1);
                    }
                    float a1tot = a1 + __shfl_xor(a1, 1);
                    if ((tau & 1) == 0) {
                        if (o1 < NX * NX + NX * NU) s_Bm[o1 - NX * NX] = a1tot;
                        else s_nx[o1 - (NX * NX + NX * NU)] = sigm_scaled(a1tot);
                    }
                }
            }
            bar();

            // ===== P4: T2 = Am@qc || pm = Am@qm + Bm@u =====
            {
                int i = tid >> 5, l = tid & 31;
                float acc = 0.f;
                #pragma unroll
                for (int j = 0; j < NX; j++)
                    acc = fmaf(s_Am[i * NXP + j], s_qc[j * NXP + l], acc);
                s_T2[i * NXP + l] = acc;
            }
            if (tid < NX) {
                float acc = 0.f;
                #pragma unroll
                for (int j = 0; j < NX; j++) acc = fmaf(s_Am[tid * NXP + j], s_qm[j], acc);
                #pragma unroll
                for (int j = 0; j < NU; j++) acc = fmaf(s_Bm[tid * NU + j], s_u[j], acc);
                s_pm[tid] = acc;
                pack1_to(tid, acc, s_pmh);
            }
            bar();
        }

        // ===== P5: W1@pm || pc = psd(T2 Am^T + nx) || pm store || a load =====
        if (tid < NH) {
            const uint4* xh = (const uint4*)s_pmh;
            float acc = b1v;
            #pragma unroll
            for (int k8 = 0; k8 < 4; k8++)
                acc = dot8(W1h[k8 * NH + tid], xh[k8], acc);
            pack1_h1(tid, fmaxf(acc, 0.f), s_h1h);
        } else if (tid < 784) {
            if (t > 0) {
                const int i = iT, l = lT;
                float a_il = 0.f, a_li = 0.f;
                #pragma unroll
                for (int j = 0; j < NX; j++) {
                    a_il = fmaf(s_T2[i * NXP + j], s_Am[l * NXP + j], a_il);
                    a_li = fmaf(s_T2[l * NXP + j], s_Am[i * NXP + j], a_li);
                }
                if (i == l) {
                    s_pc[i * NXP + i] = a_il + s_nx[i] + EPSV;
                } else {
                    float v = 0.5f * (a_il + a_li);
                    s_pc[i * NXP + l] = v;
                    s_pc[l * NXP + i] = v;
                }
            }
        } else if (tid < 816) {
            __builtin_nontemporal_store(s_pm[tid - 784], out + pmO + mIdx * NX + (tid - 784));
        } else if (tid < 840) {
            s_a[tid - 816] = a[mIdx * NA + (tid - 816)];
        }
        bar();

        // ===== P6: trunk (W2 from LDS) || pc store =====
        {
            __builtin_nontemporal_store(s_pc[(tid >> 5) * NXP + (tid & 31)],
                                        out + pcO + mIdx * (NX * NX) + tid);
            const uint4* xh = (const uint4*)s_h1h;
            float acc = 0.f;
            #pragma unroll
            for (int kk = 0; kk < 8; kk++)
                acc = dot8(s_w2[kk * 1024 + tid], xh[(tid & 3) * 9 + kk], acc);
            acc += __shfl_xor(acc, 1);
            acc += __shfl_xor(acc, 2);
            float v = fmaxf(acc + b2v, 0.f);
            unsigned short us = f2h(v);
            int pi = __shfl_xor((int)us, 4);
            if ((tid & 7) == 0) s_h2h[tid >> 3] = (uint32)us | ((uint32)pi << 16);
        }
        bar();

        // ===== P7: head2 (C | na) — pure load/compute phase =====
        if (tid < H2P) {
            const uint4* xh = (const uint4*)s_h2h;
            float acc = bh2v;
            #pragma unroll 8
            for (int k8 = 0; k8 < 32; k8++)
                acc = dot8(H2h[k8 * H2P + tid], xh[k8], acc);
            if (tid < NA * NX) {
                int i = tid >> 5, l = tid & 31;
                s_C[i * NXP + l] = acc;
            } else if (tid < H2O) {
                s_na[tid - NA * NX] = sigm_scaled(acc);
            }
        }
        bar();

        // ===== P8: T1 = C@pc || innov = a - C@pm =====
        if (tid < NA * NX) {
            int i = tid >> 5, l = tid & 31;
            float acc = 0.f;
            #pragma unroll
            for (int k = 0; k < NX; k++)
                acc = fmaf(s_C[i * NXP + k], s_pc[k * NXP + l], acc);
            s_T1[i * NXP + l] = acc;
        } else if (tid < NA * NX + NA) {
            int i = tid - NA * NX;
            float acc = s_a[i];
            #pragma unroll
            for (int j = 0; j < NX; j++)
                acc = fmaf(-s_C[i * NXP + j], s_pm[j], acc);
            s_innov[i] = acc;
        }
        bar();

        // ===== P9: S = T1 @ C^T + diag(na) =====
        if (tid < 300) {
            float acc = 0.f;
            #pragma unroll
            for (int j = 0; j < NX; j++)
                acc = fmaf(s_T1[iS * NXP + j], s_C[lS * NXP + j], acc);
            if (iS == lS) acc += s_na[iS];
            s_S[iS * NA + lS] = acc;
            s_S[lS * NA + iS] = acc;
        }
        bar();

        // ===== P10: single-wave Gauss-Jordan: Y = S^-1 T1, qm folded in =====
        if (tid < 64) {
            const int j = tid;
            float r[NA];
            #pragma unroll
            for (int i = 0; i < NA; i++) {
                float v = 0.f;
                if (j < NA) v = s_S[i * NA + j];
                else if (j < NA + NX) v = s_T1[i * NXP + (j - NA)];
                r[i] = v;
            }
            #pragma unroll
            for (int k = 0; k < NA; k++) {
                float piv = __shfl(r[k], k);
                float ip = 1.0f / piv;
                r[k] *= ip;
                #pragma unroll
                for (int i = 0; i < NA; i++) {
                    if (i == k) continue;
                    float f = __shfl(r[i], k);
                    r[i] = fmaf(-f, r[k], r[i]);
                }
            }
            if (j >= NA && j < NA + NX) {
                const int x = j - NA;
                float acc = s_pm[x];
                #pragma unroll
                for (int i = 0; i < NA; i++) {
                    s_Y[i * NX + x] = r[i];
                    acc = fmaf(r[i], s_innov[i], acc);
                }
                s_qm[x] = acc;
                unsigned short us = f2h(acc);
                int pi = __shfl_xor((int)us, 1);
                if ((x & 1) == 0) s_qmh[x >> 1] = (uint32)us | ((uint32)pi << 16);
            }
        }
        // Per-step store-queue drain on otherwise-idle waves.
        asm volatile("s_waitcnt vmcnt(0)" ::: "memory");
        bar();
    }

    // Epilogue: qc for t = NT-1, then store qm/qc (coalesced)
    if (tid >= 256 && tid < 784) {
        const int i = iT, l = lT;
        float t_il = 0.f, t_li = 0.f;
        #pragma unroll
        for (int q = 0; q < NA; q++) {
            t_il = fmaf(s_Y[q * NX + i], s_T1[q * NXP + l], t_il);
            t_li = fmaf(s_Y[q * NX + l], s_T1[q * NXP + i], t_li);
        }
        if (i == l) {
            s_qc[i * NXP + i] = s_pc[i * NXP + i] - t_il + EPSV;
        } else {
            float v = 0.5f * ((s_pc[i * NXP + l] - t_il) + (s_pc[l * NXP + i] - t_li));
            s_qc[i * NXP + l] = v;
            s_qc[l * NXP + i] = v;
        }
    }
    bar();
    {
        const size_t mLast = (size_t)(NT - 1) * NB + b;
        for (int s = tid; s < NX + NX * NX; s += 1024) {
            if (s < NX)
                __builtin_nontemporal_store(s_qm[s], out + qmO + mLast * NX + s);
            else {
                int o = s - NX, i = o >> 5, l = o & 31;
                __builtin_nontemporal_store(s_qc[i * NXP + l],
                                            out + qcO + mLast * NX * NX + o);
            }
        }
    }
}

// ---------------------------------------------------------------------------
extern "C" void kernel_launch(void* const* d_in, const int* in_sizes, int n_in,
                              void* d_out, int out_size, void* d_ws, size_t ws_size,
                              hipStream_t stream)
{
    const float* u    = (const float*)d_in[0];
    const float* a    = (const float*)d_in[1];
    const float* W1   = (const float*)d_in[2];
    const float* b1   = (const float*)d_in[3];
    const float* W2   = (const float*)d_in[4];
    const float* b2   = (const float*)d_in[5];
    const float* WA   = (const float*)d_in[6];
    const float* bA   = (const float*)d_in[7];
    const float* WB   = (const float*)d_in[8];
    const float* bB   = (const float*)d_in[9];
    const float* WC   = (const float*)d_in[10];
    const float* bC   = (const float*)d_in[11];
    const float* Wnx  = (const float*)d_in[12];
    const float* bnx  = (const float*)d_in[13];
    const float* Wna  = (const float*)d_in[14];
    const float* bna  = (const float*)d_in[15];
    const float* alph = (const float*)d_in[16];

    uint32* wsu = (uint32*)d_ws;
    float* out = (float*)d_out;

    auto pk = [&](const float* src, int O, int K, size_t dst_off, int LDP, int off) {
        int n = O * (K / 2);
        pack_half_off<<<(n + 255) / 256, 256, 0, stream>>>(src, wsu + dst_off, O, K, LDP, off);
    };
    pk(W1,  NH,      NX, OFF_W1, NH,  0);
    pk(W2,  NH,      NH, OFF_W2, NH,  0);
    pk(WA,  NX * NX, NH, OFF_H1, H1P, 0);
    pk(WB,  NX * NU, NH, OFF_H1, H1P, NX * NX);
    pk(Wnx, NX,      NH, OFF_H1, H1P, NX * NX + NX * NU);
    pk(WC,  NA * NX, NH, OFF_H2, H2P, 0);
    pk(Wna, NA,      NH, OFF_H2, H2P, NA * NX);

    pack_bias3<<<(H1O + 255) / 256, 256, 0, stream>>>(bA, NX * NX, bB, NX * NU, bnx, NX,
                                                      (float*)(wsu + OFF_B1));
    pack_bias3<<<(H2O + 255) / 256, 256, 0, stream>>>(bC, NA * NX, bna, NA, nullptr, 0,
                                                      (float*)(wsu + OFF_B2));

    kf_kernel<<<NB, 1024, 0, stream>>>(u, a, wsu, b1, b2, alph, out);
}

// Round 10
// 3639.729 us; speedup vs baseline: 1.9138x; 1.0938x over previous
//
#include <hip/hip_runtime.h>
#include <hip/hip_bf16.h>
#include <math.h>

typedef unsigned int uint32;
typedef _Float16 h2_t __attribute__((ext_vector_type(2)));

// Problem constants
static constexpr int NX = 32;    // state dim
static constexpr int NU = 8;     // control dim
static constexpr int NA = 24;    // obs dim
static constexpr int NH = 256;   // hidden
static constexpr int NT = 128;   // time steps
static constexpr int NB = 256;   // batch
static constexpr int NXP = 33;   // ODD padded row stride (bank-safe)
static constexpr float MINV = 0.01f, MAXV = 1.0f, EPSV = 1e-6f;

// Padded head widths (outputs)
static constexpr int H1O = NX*NX + NX*NU + NX;   // 1312 real
static constexpr int H1P = 1344;                 // padded
static constexpr int H2O = NA*NX + NA;           // 792 real
static constexpr int H2P = 800;                  // padded

// Workspace layout in uint32 units (all 16B aligned)
static constexpr size_t OFF_W1 = 0;
static constexpr size_t OFF_W2 = 4096;
static constexpr size_t OFF_H1 = OFF_W2 + 32768;
static constexpr size_t OFF_H2 = OFF_H1 + 172032;
static constexpr size_t OFF_B1 = OFF_H2 + 102400;
static constexpr size_t OFF_B2 = OFF_B1 + 1344;

// ---------------------------------------------------------------------------
__global__ void pack_half_off(const float* __restrict__ src, uint32* __restrict__ dst,
                              int O, int K, int LDP, int off)
{
    int idx = blockIdx.x * blockDim.x + threadIdx.x;
    int K2 = K >> 1;
    if (idx >= O * K2) return;
    int kk = idx % K2;
    int o  = idx / K2;
    int k  = kk * 2;
    int k8 = k >> 3, q = (k >> 1) & 3;
    _Float16 a = (_Float16)src[o * K + k];
    _Float16 b = (_Float16)src[o * K + k + 1];
    uint32 val = (uint32)__builtin_bit_cast(unsigned short, a)
               | ((uint32)__builtin_bit_cast(unsigned short, b) << 16);
    dst[((size_t)k8 * LDP + off + o) * 4 + q] = val;
}

__global__ void pack_bias3(const float* __restrict__ s0, int n0,
                           const float* __restrict__ s1, int n1,
                           const float* __restrict__ s2, int n2,
                           float* __restrict__ dst)
{
    int i = blockIdx.x * blockDim.x + threadIdx.x;
    if (i < n0) dst[i] = s0[i];
    else if (i < n0 + n1) dst[i] = s1[i - n0];
    else if (i < n0 + n1 + n2) dst[i] = s2[i - n0 - n1];
}

// ---------------------------------------------------------------------------
__device__ __forceinline__ float dot2(uint32 w, uint32 x, float acc)
{
#if __has_builtin(__builtin_amdgcn_fdot2)
    return __builtin_amdgcn_fdot2(__builtin_bit_cast(h2_t, w),
                                  __builtin_bit_cast(h2_t, x), acc, false);
#else
    h2_t a = __builtin_bit_cast(h2_t, w), b = __builtin_bit_cast(h2_t, x);
    return acc + (float)a[0] * (float)b[0] + (float)a[1] * (float)b[1];
#endif
}

__device__ __forceinline__ float dot8(uint4 w, uint4 x, float acc)
{
    acc = dot2(w.x, x.x, acc);
    acc = dot2(w.y, x.y, acc);
    acc = dot2(w.z, x.z, acc);
    acc = dot2(w.w, x.w, acc);
    return acc;
}

__device__ __forceinline__ void tri_decode(int p, int& l, int& i)
{
    int lo = (int)((sqrtf(8.f * (float)p + 1.f) - 1.f) * 0.5f);
    while ((lo + 1) * (lo + 2) / 2 <= p) lo++;
    while (lo * (lo + 1) / 2 > p) lo--;
    l = lo;
    i = p - lo * (lo + 1) / 2;
}

__device__ __forceinline__ float sigm_scaled(float z)
{
    return MINV + (MAXV - MINV) / (1.f + expf(-z));
}

__device__ __forceinline__ unsigned short f2h(float v)
{
    _Float16 h = (_Float16)v;
    return __builtin_bit_cast(unsigned short, h);
}

__device__ __forceinline__ void pack1_to(int tid, float v, uint32* d)
{
    unsigned short us = f2h(v);
    int pi = __shfl_xor((int)us, 1);
    if ((tid & 1) == 0)
        d[tid >> 1] = (uint32)us | ((uint32)pi << 16);
}

// Padded h1 writer: logical uint4 index g*8+kk maps to physical g*9+kk
// (one uint4 gap per 64-element split-K group). The trunk's quad read then
// hits banks {4g+4kk..} all distinct -> conflict-free. Counter-verified:
// SQ_LDS_BANK_CONFLICT 39.4M (R2) -> 5.98M (R7), dur -34us.
__device__ __forceinline__ void pack1_h1(int tid, float v, uint32* d)
{
    unsigned short us = f2h(v);
    int pi = __shfl_xor((int)us, 1);
    if ((tid & 1) == 0)
        d[(tid >> 1) + ((tid >> 6) << 2)] = (uint32)us | ((uint32)pi << 16);
}

// LDS-only fence + block barrier (no vmcnt drain). Stores live only in
// phases without latency-critical global loads; one vmcnt(0) per step (P10)
// bounds store-queue buildup.
__device__ __forceinline__ void bar()
{
    asm volatile("s_waitcnt lgkmcnt(0)" ::: "memory");
    __builtin_amdgcn_s_barrier();
    asm volatile("" ::: "memory");
}

// ---------------------------------------------------------------------------
// 1 batch element per block, 1024 threads, 1 block/CU. 10 barriers/step.
// CONVERGED STATE (R0-R9 evidence):
// - SPILL RULE (R4/R5/R8, FETCH 16MB -> 3.5-4.5GB signature): any
//   compile-time-constant batch of >= ~12 uint4 global loads hoistable as a
//   group (prefetch arrays, fully-unrolled 16-load loops) spills to scratch
//   at the pinned VGPR=64 allocation. Streamed loops, partial unroll <= 8 OK.
// - P3/P7 head phases are per-CU L2-BW-bound (R8/R9: load-rebalance with
//   equal bytes regressed) — lane-level load balancing cannot help.
// - 10 barriers/step is the dependency-chain floor; TLP capped at 16
//   waves/CU (grid = NB = #CUs, 1024-thread blocks, 159KB LDS).
__global__ __launch_bounds__(1024, 4) void kf_kernel(
    const float* __restrict__ u, const float* __restrict__ a,
    const uint32* __restrict__ wsu,
    const float* __restrict__ b1, const float* __restrict__ b2,
    const float* __restrict__ alpha_p,
    float* __restrict__ out)
{
    const int tid = threadIdx.x;
    const int b   = blockIdx.x;
    const float alpha = alpha_p[0];

    const uint4* W1h = (const uint4*)(wsu + OFF_W1);
    const uint4* W2h = (const uint4*)(wsu + OFF_W2);
    const uint4* H1h = (const uint4*)(wsu + OFF_H1);
    const uint4* H2h = (const uint4*)(wsu + OFF_H2);
    const float* BH1 = (const float*)(wsu + OFF_B1);
    const float* BH2 = (const float*)(wsu + OFF_B2);

    // W2 resident in LDS: s_w2[kk*1024 + tid]; wave reads are 1KB contiguous.
    __shared__ alignas(16) uint4 s_w2[8 * 1024];          // 131072 B

    __shared__ alignas(16) uint32 s_h1h[144];             // padded (9 uint4 / group)
    __shared__ alignas(16) uint32 s_h2h[NH / 2];
    __shared__ alignas(16) uint32 s_qmh[NX / 2];
    __shared__ alignas(16) uint32 s_pmh[NX / 2];
    __shared__ alignas(16) float s_Am[NX * NXP];
    __shared__ float s_Bm[NX * NU];
    __shared__ float s_nx[NX];
    __shared__ alignas(16) float s_C[NA * NXP];
    __shared__ float s_na[NA];
    __shared__ float s_qm[NX];
    __shared__ alignas(16) float s_qc[NX * NXP];
    __shared__ float s_pm[NX];
    __shared__ alignas(16) float s_pc[NX * NXP];
    __shared__ alignas(16) float s_T2[NX * NXP];
    __shared__ alignas(16) float s_T1[NA * NXP];
    __shared__ float s_S[NA * NA];
    __shared__ float s_Y[NA * NX];
    __shared__ float s_innov[NA];
    __shared__ float s_a[NA], s_u[NU];

    const size_t pmO = 0;
    const size_t pcO = (size_t)NT * NB * NX;
    const size_t qmO = pcO + (size_t)NT * NB * NX * NX;
    const size_t qcO = qmO + (size_t)NT * NB * NX;

    // One-time: stage W2 into LDS in the wave-contiguous layout.
    {
        const int o = tid >> 2, g = tid & 3;
        #pragma unroll
        for (int kk = 0; kk < 8; kk++)
            s_w2[kk * 1024 + tid] = W2h[(g * 8 + kk) * NH + o];
    }

    // Hoisted per-lane constants (invariant over t)
    const float b1v  = (tid < NH) ? b1[tid] : 0.f;
    const float b2v  = b2[tid >> 2];
    const float bh1a = BH1[tid];
    const float bh1b = (tid + 1024 < H1O) ? BH1[tid + 1024] : 0.f;
    const float bh2v = (tid < H2P) ? BH2[tid] : 0.f;

    // Hoisted triangular index maps (constant over t)
    int iT = 0, lT = 0;                 // 528-item 32x32 triangle on lanes 256-783
    if (tid >= 256 && tid < 784) tri_decode(tid - 256, lT, iT);
    int iS = 0, lS = 0;                 // 300-item 24x24 triangle, tid<300
    if (tid < 300) tri_decode(tid, lS, iS);

    for (int t = 0; t < NT; ++t) {
        const size_t mIdx = (size_t)t * NB + b;

        if (t == 0) {
            if (tid < NX) s_pm[tid] = 0.f;
            if (tid < NX / 2) s_pmh[tid] = 0u;
            {
                int i = tid >> 5, l = tid & 31;
                s_pc[i * NXP + l] = (i == l) ? 1.f : 0.f;
            }
            bar();   // also covers the s_w2 staging above
        } else {
            const size_t mPrev = (size_t)(t - 1) * NB + b;

            // ===== P1: W1@qm || qc-psd (prev Y,T1,pc) || qm store || u load =====
            if (tid < NH) {
                const uint4* xh = (const uint4*)s_qmh;
                float acc = b1v;
                #pragma unroll
                for (int k8 = 0; k8 < 4; k8++)
                    acc = dot8(W1h[k8 * NH + tid], xh[k8], acc);
                pack1_h1(tid, fmaxf(acc, 0.f), s_h1h);
            } else if (tid < 784) {
                const int i = iT, l = lT;
                float t_il = 0.f, t_li = 0.f;
                #pragma unroll
                for (int q = 0; q < NA; q++) {
                    t_il = fmaf(s_Y[q * NX + i], s_T1[q * NXP + l], t_il);
                    t_li = fmaf(s_Y[q * NX + l], s_T1[q * NXP + i], t_li);
                }
                if (i == l) {
                    s_qc[i * NXP + i] = s_pc[i * NXP + i] - t_il + EPSV;
                } else {
                    float v = 0.5f * ((s_pc[i * NXP + l] - t_il) + (s_pc[l * NXP + i] - t_li));
                    s_qc[i * NXP + l] = v;
                    s_qc[l * NXP + i] = v;
                }
            } else if (tid < 816) {
                __builtin_nontemporal_store(s_qm[tid - 784], out + qmO + mPrev * NX + (tid - 784));
            } else if (tid < 824) {
                s_u[tid - 816] = u[mPrev * NU + (tid - 816)];
            }
            bar();

            // ===== P2: trunk (W2 from LDS, quad split-K) || qc store =====
            {
                __builtin_nontemporal_store(s_qc[(tid >> 5) * NXP + (tid & 31)],
                                            out + qcO + mPrev * (NX * NX) + tid);
                const uint4* xh = (const uint4*)s_h1h;
                float acc = 0.f;
                #pragma unroll
                for (int kk = 0; kk < 8; kk++)
                    acc = dot8(s_w2[kk * 1024 + tid], xh[(tid & 3) * 9 + kk], acc);
                acc += __shfl_xor(acc, 1);
                acc += __shfl_xor(acc, 2);
                float v = fmaxf(acc + b2v, 0.f);
                unsigned short us = f2h(v);
                int pi = __shfl_xor((int)us, 4);
                if ((tid & 7) == 0) s_h2h[tid >> 3] = (uint32)us | ((uint32)pi << 16);
            }
            bar();

            // ===== P3: head1 — pure load/compute phase (L2-BW-bound; fused
            //       dual-output loop maximizes loads in flight) =====
            {
                const uint4* xh = (const uint4*)s_h2h;
                int o0 = tid, o1 = tid + 1024;
                float a0 = bh1a;
                float a1 = bh1b;
                #pragma unroll 8
                for (int k8 = 0; k8 < 32; k8++) {
                    uint4 x = xh[k8];
                    a0 = dot8(H1h[k8 * H1P + o0], x, a0);
                    if (o1 < H1O) a1 = dot8(H1h[k8 * H1P + o1], x, a1);
                }
                {
                    int i = o0 >> 5, l = o0 & 31;
                    s_Am[i * NXP + l] = ((i == l) ? 1.f : 0.f) + alpha * a0;
                }
                if (o1 < H1O) {
                    if (o1 < NX * NX + NX * NU) s_Bm[o1 - NX * NX] = a1;
                    else s_nx[o1 - (NX * NX + NX * NU)] = sigm_scaled(a1);
                }
            }
            bar();

            // ===== P4: T2 = Am@qc || pm = Am@qm + Bm@u =====
            {
                int i = tid >> 5, l = tid & 31;
                float acc = 0.f;
                #pragma unroll
                for (int j = 0; j < NX; j++)
                    acc = fmaf(s_Am[i * NXP + j], s_qc[j * NXP + l], acc);
                s_T2[i * NXP + l] = acc;
            }
            if (tid < NX) {
                float acc = 0.f;
                #pragma unroll
                for (int j = 0; j < NX; j++) acc = fmaf(s_Am[tid * NXP + j], s_qm[j], acc);
                #pragma unroll
                for (int j = 0; j < NU; j++) acc = fmaf(s_Bm[tid * NU + j], s_u[j], acc);
                s_pm[tid] = acc;
                pack1_to(tid, acc, s_pmh);
            }
            bar();
        }

        // ===== P5: W1@pm || pc = psd(T2 Am^T + nx) || pm store || a load =====
        if (tid < NH) {
            const uint4* xh = (const uint4*)s_pmh;
            float acc = b1v;
            #pragma unroll
            for (int k8 = 0; k8 < 4; k8++)
                acc = dot8(W1h[k8 * NH + tid], xh[k8], acc);
            pack1_h1(tid, fmaxf(acc, 0.f), s_h1h);
        } else if (tid < 784) {
            if (t > 0) {
                const int i = iT, l = lT;
                float a_il = 0.f, a_li = 0.f;
                #pragma unroll
                for (int j = 0; j < NX; j++) {
                    a_il = fmaf(s_T2[i * NXP + j], s_Am[l * NXP + j], a_il);
                    a_li = fmaf(s_T2[l * NXP + j], s_Am[i * NXP + j], a_li);
                }
                if (i == l) {
                    s_pc[i * NXP + i] = a_il + s_nx[i] + EPSV;
                } else {
                    float v = 0.5f * (a_il + a_li);
                    s_pc[i * NXP + l] = v;
                    s_pc[l * NXP + i] = v;
                }
            }
        } else if (tid < 816) {
            __builtin_nontemporal_store(s_pm[tid - 784], out + pmO + mIdx * NX + (tid - 784));
        } else if (tid < 840) {
            s_a[tid - 816] = a[mIdx * NA + (tid - 816)];
        }
        bar();

        // ===== P6: trunk (W2 from LDS) || pc store =====
        {
            __builtin_nontemporal_store(s_pc[(tid >> 5) * NXP + (tid & 31)],
                                        out + pcO + mIdx * (NX * NX) + tid);
            const uint4* xh = (const uint4*)s_h1h;
            float acc = 0.f;
            #pragma unroll
            for (int kk = 0; kk < 8; kk++)
                acc = dot8(s_w2[kk * 1024 + tid], xh[(tid & 3) * 9 + kk], acc);
            acc += __shfl_xor(acc, 1);
            acc += __shfl_xor(acc, 2);
            float v = fmaxf(acc + b2v, 0.f);
            unsigned short us = f2h(v);
            int pi = __shfl_xor((int)us, 4);
            if ((tid & 7) == 0) s_h2h[tid >> 3] = (uint32)us | ((uint32)pi << 16);
        }
        bar();

        // ===== P7: head2 (C | na) — pure load/compute phase =====
        if (tid < H2P) {
            const uint4* xh = (const uint4*)s_h2h;
            float acc = bh2v;
            #pragma unroll 8
            for (int k8 = 0; k8 < 32; k8++)
                acc = dot8(H2h[k8 * H2P + tid], xh[k8], acc);
            if (tid < NA * NX) {
                int i = tid >> 5, l = tid & 31;
                s_C[i * NXP + l] = acc;
            } else if (tid < H2O) {
                s_na[tid - NA * NX] = sigm_scaled(acc);
            }
        }
        bar();

        // ===== P8: T1 = C@pc || innov = a - C@pm =====
        if (tid < NA * NX) {
            int i = tid >> 5, l = tid & 31;
            float acc = 0.f;
            #pragma unroll
            for (int k = 0; k < NX; k++)
                acc = fmaf(s_C[i * NXP + k], s_pc[k * NXP + l], acc);
            s_T1[i * NXP + l] = acc;
        } else if (tid < NA * NX + NA) {
            int i = tid - NA * NX;
            float acc = s_a[i];
            #pragma unroll
            for (int j = 0; j < NX; j++)
                acc = fmaf(-s_C[i * NXP + j], s_pm[j], acc);
            s_innov[i] = acc;
        }
        bar();

        // ===== P9: S = T1 @ C^T + diag(na) =====
        if (tid < 300) {
            float acc = 0.f;
            #pragma unroll
            for (int j = 0; j < NX; j++)
                acc = fmaf(s_T1[iS * NXP + j], s_C[lS * NXP + j], acc);
            if (iS == lS) acc += s_na[iS];
            s_S[iS * NA + lS] = acc;
            s_S[lS * NA + iS] = acc;
        }
        bar();

        // ===== P10: single-wave Gauss-Jordan: Y = S^-1 T1, qm folded in =====
        if (tid < 64) {
            const int j = tid;
            float r[NA];
            #pragma unroll
            for (int i = 0; i < NA; i++) {
                float v = 0.f;
                if (j < NA) v = s_S[i * NA + j];
                else if (j < NA + NX) v = s_T1[i * NXP + (j - NA)];
                r[i] = v;
            }
            #pragma unroll
            for (int k = 0; k < NA; k++) {
                float piv = __shfl(r[k], k);
                float ip = 1.0f / piv;
                r[k] *= ip;
                #pragma unroll
                for (int i = 0; i < NA; i++) {
                    if (i == k) continue;
                    float f = __shfl(r[i], k);
                    r[i] = fmaf(-f, r[k], r[i]);
                }
            }
            if (j >= NA && j < NA + NX) {
                const int x = j - NA;
                float acc = s_pm[x];
                #pragma unroll
                for (int i = 0; i < NA; i++) {
                    s_Y[i * NX + x] = r[i];
                    acc = fmaf(r[i], s_innov[i], acc);
                }
                s_qm[x] = acc;
                unsigned short us = f2h(acc);
                int pi = __shfl_xor((int)us, 1);
                if ((x & 1) == 0) s_qmh[x >> 1] = (uint32)us | ((uint32)pi << 16);
            }
        }
        // Per-step store-queue drain on otherwise-idle waves.
        asm volatile("s_waitcnt vmcnt(0)" ::: "memory");
        bar();
    }

    // Epilogue: qc for t = NT-1, then store qm/qc (coalesced)
    if (tid >= 256 && tid < 784) {
        const int i = iT, l = lT;
        float t_il = 0.f, t_li = 0.f;
        #pragma unroll
        for (int q = 0; q < NA; q++) {
            t_il = fmaf(s_Y[q * NX + i], s_T1[q * NXP + l], t_il);
            t_li = fmaf(s_Y[q * NX + l], s_T1[q * NXP + i], t_li);
        }
        if (i == l) {
            s_qc[i * NXP + i] = s_pc[i * NXP + i] - t_il + EPSV;
        } else {
            float v = 0.5f * ((s_pc[i * NXP + l] - t_il) + (s_pc[l * NXP + i] - t_li));
            s_qc[i * NXP + l] = v;
            s_qc[l * NXP + i] = v;
        }
    }
    bar();
    {
        const size_t mLast = (size_t)(NT - 1) * NB + b;
        for (int s = tid; s < NX + NX * NX; s += 1024) {
            if (s < NX)
                __builtin_nontemporal_store(s_qm[s], out + qmO + mLast * NX + s);
            else {
                int o = s - NX, i = o >> 5, l = o & 31;
                __builtin_nontemporal_store(s_qc[i * NXP + l],
                                            out + qcO + mLast * NX * NX + o);
            }
        }
    }
}

// ---------------------------------------------------------------------------
extern "C" void kernel_launch(void* const* d_in, const int* in_sizes, int n_in,
                              void* d_out, int out_size, void* d_ws, size_t ws_size,
                              hipStream_t stream)
{
    const float* u    = (const float*)d_in[0];
    const float* a    = (const float*)d_in[1];
    const float* W1   = (const float*)d_in[2];
    const float* b1   = (const float*)d_in[3];
    const float* W2   = (const float*)d_in[4];
    const float* b2   = (const float*)d_in[5];
    const float* WA   = (const float*)d_in[6];
    const float* bA   = (const float*)d_in[7];
    const float* WB   = (const float*)d_in[8];
    const float* bB   = (const float*)d_in[9];
    const float* WC   = (const float*)d_in[10];
    const float* bC   = (const float*)d_in[11];
    const float* Wnx  = (const float*)d_in[12];
    const float* bnx  = (const float*)d_in[13];
    const float* Wna  = (const float*)d_in[14];
    const float* bna  = (const float*)d_in[15];
    const float* alph = (const float*)d_in[16];

    uint32* wsu = (uint32*)d_ws;
    float* out = (float*)d_out;

    auto pk = [&](const float* src, int O, int K, size_t dst_off, int LDP, int off) {
        int n = O * (K / 2);
        pack_half_off<<<(n + 255) / 256, 256, 0, stream>>>(src, wsu + dst_off, O, K, LDP, off);
    };
    pk(W1,  NH,      NX, OFF_W1, NH,  0);
    pk(W2,  NH,      NH, OFF_W2, NH,  0);
    pk(WA,  NX * NX, NH, OFF_H1, H1P, 0);
    pk(WB,  NX * NU, NH, OFF_H1, H1P, NX * NX);
    pk(Wnx, NX,      NH, OFF_H1, H1P, NX * NX + NX * NU);
    pk(WC,  NA * NX, NH, OFF_H2, H2P, 0);
    pk(Wna, NA,      NH, OFF_H2, H2P, NA * NX);

    pack_bias3<<<(H1O + 255) / 256, 256, 0, stream>>>(bA, NX * NX, bB, NX * NU, bnx, NX,
                                                      (float*)(wsu + OFF_B1));
    pack_bias3<<<(H2O + 255) / 256, 256, 0, stream>>>(bC, NA * NX, bna, NA, nullptr, 0,
                                                      (float*)(wsu + OFF_B2));

    kf_kernel<<<NB, 1024, 0, stream>>>(u, a, wsu, b1, b2, alph, out);
}

// Round 11
// 3622.417 us; speedup vs baseline: 1.9229x; 1.0048x over previous
//
#include <hip/hip_runtime.h>
#include <hip/hip_bf16.h>
#include <math.h>

typedef unsigned int uint32;
typedef _Float16 h2_t __attribute__((ext_vector_type(2)));

// Problem constants
static constexpr int NX = 32;    // state dim
static constexpr int NU = 8;     // control dim
static constexpr int NA = 24;    // obs dim
static constexpr int NH = 256;   // hidden
static constexpr int NT = 128;   // time steps
static constexpr int NB = 256;   // batch
static constexpr int NXP = 33;   // ODD padded row stride (bank-safe)
static constexpr float MINV = 0.01f, MAXV = 1.0f, EPSV = 1e-6f;

// Padded head widths (outputs)
static constexpr int H1O = NX*NX + NX*NU + NX;   // 1312 real
static constexpr int H1P = 1344;                 // padded
static constexpr int H2O = NA*NX + NA;           // 792 real
static constexpr int H2P = 800;                  // padded

// Workspace layout in uint32 units (all 16B aligned)
static constexpr size_t OFF_W1 = 0;
static constexpr size_t OFF_W2 = 4096;
static constexpr size_t OFF_H1 = OFF_W2 + 32768;
static constexpr size_t OFF_H2 = OFF_H1 + 172032;
static constexpr size_t OFF_B1 = OFF_H2 + 102400;
static constexpr size_t OFF_B2 = OFF_B1 + 1344;

// ---------------------------------------------------------------------------
__global__ void pack_half_off(const float* __restrict__ src, uint32* __restrict__ dst,
                              int O, int K, int LDP, int off)
{
    int idx = blockIdx.x * blockDim.x + threadIdx.x;
    int K2 = K >> 1;
    if (idx >= O * K2) return;
    int kk = idx % K2;
    int o  = idx / K2;
    int k  = kk * 2;
    int k8 = k >> 3, q = (k >> 1) & 3;
    _Float16 a = (_Float16)src[o * K + k];
    _Float16 b = (_Float16)src[o * K + k + 1];
    uint32 val = (uint32)__builtin_bit_cast(unsigned short, a)
               | ((uint32)__builtin_bit_cast(unsigned short, b) << 16);
    dst[((size_t)k8 * LDP + off + o) * 4 + q] = val;
}

__global__ void pack_bias3(const float* __restrict__ s0, int n0,
                           const float* __restrict__ s1, int n1,
                           const float* __restrict__ s2, int n2,
                           float* __restrict__ dst)
{
    int i = blockIdx.x * blockDim.x + threadIdx.x;
    if (i < n0) dst[i] = s0[i];
    else if (i < n0 + n1) dst[i] = s1[i - n0];
    else if (i < n0 + n1 + n2) dst[i] = s2[i - n0 - n1];
}

// ---------------------------------------------------------------------------
__device__ __forceinline__ float dot2(uint32 w, uint32 x, float acc)
{
#if __has_builtin(__builtin_amdgcn_fdot2)
    return __builtin_amdgcn_fdot2(__builtin_bit_cast(h2_t, w),
                                  __builtin_bit_cast(h2_t, x), acc, false);
#else
    h2_t a = __builtin_bit_cast(h2_t, w), b = __builtin_bit_cast(h2_t, x);
    return acc + (float)a[0] * (float)b[0] + (float)a[1] * (float)b[1];
#endif
}

__device__ __forceinline__ float dot8(uint4 w, uint4 x, float acc)
{
    acc = dot2(w.x, x.x, acc);
    acc = dot2(w.y, x.y, acc);
    acc = dot2(w.z, x.z, acc);
    acc = dot2(w.w, x.w, acc);
    return acc;
}

__device__ __forceinline__ void tri_decode(int p, int& l, int& i)
{
    int lo = (int)((sqrtf(8.f * (float)p + 1.f) - 1.f) * 0.5f);
    while ((lo + 1) * (lo + 2) / 2 <= p) lo++;
    while (lo * (lo + 1) / 2 > p) lo--;
    l = lo;
    i = p - lo * (lo + 1) / 2;
}

__device__ __forceinline__ float sigm_scaled(float z)
{
    return MINV + (MAXV - MINV) / (1.f + expf(-z));
}

__device__ __forceinline__ unsigned short f2h(float v)
{
    _Float16 h = (_Float16)v;
    return __builtin_bit_cast(unsigned short, h);
}

__device__ __forceinline__ void pack1_to(int tid, float v, uint32* d)
{
    unsigned short us = f2h(v);
    int pi = __shfl_xor((int)us, 1);
    if ((tid & 1) == 0)
        d[tid >> 1] = (uint32)us | ((uint32)pi << 16);
}

// Padded h1 writer: logical uint4 index g*8+kk maps to physical g*9+kk
// (one uint4 gap per 64-element split-K group). The trunk's quad read then
// hits banks {4g+4kk..} all distinct -> conflict-free. Counter-verified:
// SQ_LDS_BANK_CONFLICT 39.4M (R2) -> 5.98M (R7), dur -34us.
__device__ __forceinline__ void pack1_h1(int tid, float v, uint32* d)
{
    unsigned short us = f2h(v);
    int pi = __shfl_xor((int)us, 1);
    if ((tid & 1) == 0)
        d[(tid >> 1) + ((tid >> 6) << 2)] = (uint32)us | ((uint32)pi << 16);
}

// LDS-only fence + block barrier (no vmcnt drain). Stores live only in
// phases without latency-critical global loads; one vmcnt(0) per step (P10)
// bounds store-queue buildup.
__device__ __forceinline__ void bar()
{
    asm volatile("s_waitcnt lgkmcnt(0)" ::: "memory");
    __builtin_amdgcn_s_barrier();
    asm volatile("" ::: "memory");
}

// ---------------------------------------------------------------------------
// 1 batch element per block, 1024 threads, 1 block/CU. 10 barriers/step.
// CONVERGED STRUCTURE (R0-R10 evidence):
// - SPILL RULE (R4/R5/R8, FETCH 16MB -> 3.5-4.5GB signature): source-level
//   register prefetch arrays / fully-unrolled 16-load batches spill at a
//   64-VGPR allocation. Streamed loops with partial unroll <= 8 are safe.
// - P3/P7 head phases: lane-level load rebalancing regressed (R9).
// - 10 barriers/step is the dependency-chain floor.
// R11 change (single variable): __launch_bounds__(1024,4) ->
// __launch_bounds__(1024) + amdgpu_waves_per_eu(4,4). LDS (159KB) already
// caps the CU at 1 block = 4 waves/EU, so actual occupancy is unchanged;
// pinning max waves/EU tells the register allocator the TRUE occupancy so
// it can use up to 128 VGPRs instead of heuristically pinning 64 — letting
// the compiler's own scheduler keep more head-loop loads in flight (the
// mechanism R4/R5 attempted manually and lost to spills).
__global__ __launch_bounds__(1024)
__attribute__((amdgpu_waves_per_eu(4, 4)))
void kf_kernel(
    const float* __restrict__ u, const float* __restrict__ a,
    const uint32* __restrict__ wsu,
    const float* __restrict__ b1, const float* __restrict__ b2,
    const float* __restrict__ alpha_p,
    float* __restrict__ out)
{
    const int tid = threadIdx.x;
    const int b   = blockIdx.x;
    const float alpha = alpha_p[0];

    const uint4* W1h = (const uint4*)(wsu + OFF_W1);
    const uint4* W2h = (const uint4*)(wsu + OFF_W2);
    const uint4* H1h = (const uint4*)(wsu + OFF_H1);
    const uint4* H2h = (const uint4*)(wsu + OFF_H2);
    const float* BH1 = (const float*)(wsu + OFF_B1);
    const float* BH2 = (const float*)(wsu + OFF_B2);

    // W2 resident in LDS: s_w2[kk*1024 + tid]; wave reads are 1KB contiguous.
    __shared__ alignas(16) uint4 s_w2[8 * 1024];          // 131072 B

    __shared__ alignas(16) uint32 s_h1h[144];             // padded (9 uint4 / group)
    __shared__ alignas(16) uint32 s_h2h[NH / 2];
    __shared__ alignas(16) uint32 s_qmh[NX / 2];
    __shared__ alignas(16) uint32 s_pmh[NX / 2];
    __shared__ alignas(16) float s_Am[NX * NXP];
    __shared__ float s_Bm[NX * NU];
    __shared__ float s_nx[NX];
    __shared__ alignas(16) float s_C[NA * NXP];
    __shared__ float s_na[NA];
    __shared__ float s_qm[NX];
    __shared__ alignas(16) float s_qc[NX * NXP];
    __shared__ float s_pm[NX];
    __shared__ alignas(16) float s_pc[NX * NXP];
    __shared__ alignas(16) float s_T2[NX * NXP];
    __shared__ alignas(16) float s_T1[NA * NXP];
    __shared__ float s_S[NA * NA];
    __shared__ float s_Y[NA * NX];
    __shared__ float s_innov[NA];
    __shared__ float s_a[NA], s_u[NU];

    const size_t pmO = 0;
    const size_t pcO = (size_t)NT * NB * NX;
    const size_t qmO = pcO + (size_t)NT * NB * NX * NX;
    const size_t qcO = qmO + (size_t)NT * NB * NX;

    // One-time: stage W2 into LDS in the wave-contiguous layout.
    {
        const int o = tid >> 2, g = tid & 3;
        #pragma unroll
        for (int kk = 0; kk < 8; kk++)
            s_w2[kk * 1024 + tid] = W2h[(g * 8 + kk) * NH + o];
    }

    // Hoisted per-lane constants (invariant over t)
    const float b1v  = (tid < NH) ? b1[tid] : 0.f;
    const float b2v  = b2[tid >> 2];
    const float bh1a = BH1[tid];
    const float bh1b = (tid + 1024 < H1O) ? BH1[tid + 1024] : 0.f;
    const float bh2v = (tid < H2P) ? BH2[tid] : 0.f;

    // Hoisted triangular index maps (constant over t)
    int iT = 0, lT = 0;                 // 528-item 32x32 triangle on lanes 256-783
    if (tid >= 256 && tid < 784) tri_decode(tid - 256, lT, iT);
    int iS = 0, lS = 0;                 // 300-item 24x24 triangle, tid<300
    if (tid < 300) tri_decode(tid, lS, iS);

    for (int t = 0; t < NT; ++t) {
        const size_t mIdx = (size_t)t * NB + b;

        if (t == 0) {
            if (tid < NX) s_pm[tid] = 0.f;
            if (tid < NX / 2) s_pmh[tid] = 0u;
            {
                int i = tid >> 5, l = tid & 31;
                s_pc[i * NXP + l] = (i == l) ? 1.f : 0.f;
            }
            bar();   // also covers the s_w2 staging above
        } else {
            const size_t mPrev = (size_t)(t - 1) * NB + b;

            // ===== P1: W1@qm || qc-psd (prev Y,T1,pc) || qm store || u load =====
            if (tid < NH) {
                const uint4* xh = (const uint4*)s_qmh;
                float acc = b1v;
                #pragma unroll
                for (int k8 = 0; k8 < 4; k8++)
                    acc = dot8(W1h[k8 * NH + tid], xh[k8], acc);
                pack1_h1(tid, fmaxf(acc, 0.f), s_h1h);
            } else if (tid < 784) {
                const int i = iT, l = lT;
                float t_il = 0.f, t_li = 0.f;
                #pragma unroll
                for (int q = 0; q < NA; q++) {
                    t_il = fmaf(s_Y[q * NX + i], s_T1[q * NXP + l], t_il);
                    t_li = fmaf(s_Y[q * NX + l], s_T1[q * NXP + i], t_li);
                }
                if (i == l) {
                    s_qc[i * NXP + i] = s_pc[i * NXP + i] - t_il + EPSV;
                } else {
                    float v = 0.5f * ((s_pc[i * NXP + l] - t_il) + (s_pc[l * NXP + i] - t_li));
                    s_qc[i * NXP + l] = v;
                    s_qc[l * NXP + i] = v;
                }
            } else if (tid < 816) {
                __builtin_nontemporal_store(s_qm[tid - 784], out + qmO + mPrev * NX + (tid - 784));
            } else if (tid < 824) {
                s_u[tid - 816] = u[mPrev * NU + (tid - 816)];
            }
            bar();

            // ===== P2: trunk (W2 from LDS, quad split-K) || qc store =====
            {
                __builtin_nontemporal_store(s_qc[(tid >> 5) * NXP + (tid & 31)],
                                            out + qcO + mPrev * (NX * NX) + tid);
                const uint4* xh = (const uint4*)s_h1h;
                float acc = 0.f;
                #pragma unroll
                for (int kk = 0; kk < 8; kk++)
                    acc = dot8(s_w2[kk * 1024 + tid], xh[(tid & 3) * 9 + kk], acc);
                acc += __shfl_xor(acc, 1);
                acc += __shfl_xor(acc, 2);
                float v = fmaxf(acc + b2v, 0.f);
                unsigned short us = f2h(v);
                int pi = __shfl_xor((int)us, 4);
                if ((tid & 7) == 0) s_h2h[tid >> 3] = (uint32)us | ((uint32)pi << 16);
            }
            bar();

            // ===== P3: head1 — pure load/compute phase (fused dual-output
            //       loop; deeper load batching now enabled by 128-reg budget) =====
            {
                const uint4* xh = (const uint4*)s_h2h;
                int o0 = tid, o1 = tid + 1024;
                float a0 = bh1a;
                float a1 = bh1b;
                #pragma unroll 8
                for (int k8 = 0; k8 < 32; k8++) {
                    uint4 x = xh[k8];
                    a0 = dot8(H1h[k8 * H1P + o0], x, a0);
                    if (o1 < H1O) a1 = dot8(H1h[k8 * H1P + o1], x, a1);
                }
                {
                    int i = o0 >> 5, l = o0 & 31;
                    s_Am[i * NXP + l] = ((i == l) ? 1.f : 0.f) + alpha * a0;
                }
                if (o1 < H1O) {
                    if (o1 < NX * NX + NX * NU) s_Bm[o1 - NX * NX] = a1;
                    else s_nx[o1 - (NX * NX + NX * NU)] = sigm_scaled(a1);
                }
            }
            bar();

            // ===== P4: T2 = Am@qc || pm = Am@qm + Bm@u =====
            {
                int i = tid >> 5, l = tid & 31;
                float acc = 0.f;
                #pragma unroll
                for (int j = 0; j < NX; j++)
                    acc = fmaf(s_Am[i * NXP + j], s_qc[j * NXP + l], acc);
                s_T2[i * NXP + l] = acc;
            }
            if (tid < NX) {
                float acc = 0.f;
                #pragma unroll
                for (int j = 0; j < NX; j++) acc = fmaf(s_Am[tid * NXP + j], s_qm[j], acc);
                #pragma unroll
                for (int j = 0; j < NU; j++) acc = fmaf(s_Bm[tid * NU + j], s_u[j], acc);
                s_pm[tid] = acc;
                pack1_to(tid, acc, s_pmh);
            }
            bar();
        }

        // ===== P5: W1@pm || pc = psd(T2 Am^T + nx) || pm store || a load =====
        if (tid < NH) {
            const uint4* xh = (const uint4*)s_pmh;
            float acc = b1v;
            #pragma unroll
            for (int k8 = 0; k8 < 4; k8++)
                acc = dot8(W1h[k8 * NH + tid], xh[k8], acc);
            pack1_h1(tid, fmaxf(acc, 0.f), s_h1h);
        } else if (tid < 784) {
            if (t > 0) {
                const int i = iT, l = lT;
                float a_il = 0.f, a_li = 0.f;
                #pragma unroll
                for (int j = 0; j < NX; j++) {
                    a_il = fmaf(s_T2[i * NXP + j], s_Am[l * NXP + j], a_il);
                    a_li = fmaf(s_T2[l * NXP + j], s_Am[i * NXP + j], a_li);
                }
                if (i == l) {
                    s_pc[i * NXP + i] = a_il + s_nx[i] + EPSV;
                } else {
                    float v = 0.5f * (a_il + a_li);
                    s_pc[i * NXP + l] = v;
                    s_pc[l * NXP + i] = v;
                }
            }
        } else if (tid < 816) {
            __builtin_nontemporal_store(s_pm[tid - 784], out + pmO + mIdx * NX + (tid - 784));
        } else if (tid < 840) {
            s_a[tid - 816] = a[mIdx * NA + (tid - 816)];
        }
        bar();

        // ===== P6: trunk (W2 from LDS) || pc store =====
        {
            __builtin_nontemporal_store(s_pc[(tid >> 5) * NXP + (tid & 31)],
                                        out + pcO + mIdx * (NX * NX) + tid);
            const uint4* xh = (const uint4*)s_h1h;
            float acc = 0.f;
            #pragma unroll
            for (int kk = 0; kk < 8; kk++)
                acc = dot8(s_w2[kk * 1024 + tid], xh[(tid & 3) * 9 + kk], acc);
            acc += __shfl_xor(acc, 1);
            acc += __shfl_xor(acc, 2);
            float v = fmaxf(acc + b2v, 0.f);
            unsigned short us = f2h(v);
            int pi = __shfl_xor((int)us, 4);
            if ((tid & 7) == 0) s_h2h[tid >> 3] = (uint32)us | ((uint32)pi << 16);
        }
        bar();

        // ===== P7: head2 (C | na) — pure load/compute phase =====
        if (tid < H2P) {
            const uint4* xh = (const uint4*)s_h2h;
            float acc = bh2v;
            #pragma unroll 8
            for (int k8 = 0; k8 < 32; k8++)
                acc = dot8(H2h[k8 * H2P + tid], xh[k8], acc);
            if (tid < NA * NX) {
                int i = tid >> 5, l = tid & 31;
                s_C[i * NXP + l] = acc;
            } else if (tid < H2O) {
                s_na[tid - NA * NX] = sigm_scaled(acc);
            }
        }
        bar();

        // ===== P8: T1 = C@pc || innov = a - C@pm =====
        if (tid < NA * NX) {
            int i = tid >> 5, l = tid & 31;
            float acc = 0.f;
            #pragma unroll
            for (int k = 0; k < NX; k++)
                acc = fmaf(s_C[i * NXP + k], s_pc[k * NXP + l], acc);
            s_T1[i * NXP + l] = acc;
        } else if (tid < NA * NX + NA) {
            int i = tid - NA * NX;
            float acc = s_a[i];
            #pragma unroll
            for (int j = 0; j < NX; j++)
                acc = fmaf(-s_C[i * NXP + j], s_pm[j], acc);
            s_innov[i] = acc;
        }
        bar();

        // ===== P9: S = T1 @ C^T + diag(na) =====
        if (tid < 300) {
            float acc = 0.f;
            #pragma unroll
            for (int j = 0; j < NX; j++)
                acc = fmaf(s_T1[iS * NXP + j], s_C[lS * NXP + j], acc);
            if (iS == lS) acc += s_na[iS];
            s_S[iS * NA + lS] = acc;
            s_S[lS * NA + iS] = acc;
        }
        bar();

        // ===== P10: single-wave Gauss-Jordan: Y = S^-1 T1, qm folded in =====
        if (tid < 64) {
            const int j = tid;
            float r[NA];
            #pragma unroll
            for (int i = 0; i < NA; i++) {
                float v = 0.f;
                if (j < NA) v = s_S[i * NA + j];
                else if (j < NA + NX) v = s_T1[i * NXP + (j - NA)];
                r[i] = v;
            }
            #pragma unroll
            for (int k = 0; k < NA; k++) {
                float piv = __shfl(r[k], k);
                float ip = 1.0f / piv;
                r[k] *= ip;
                #pragma unroll
                for (int i = 0; i < NA; i++) {
                    if (i == k) continue;
                    float f = __shfl(r[i], k);
                    r[i] = fmaf(-f, r[k], r[i]);
                }
            }
            if (j >= NA && j < NA + NX) {
                const int x = j - NA;
                float acc = s_pm[x];
                #pragma unroll
                for (int i = 0; i < NA; i++) {
                    s_Y[i * NX + x] = r[i];
                    acc = fmaf(r[i], s_innov[i], acc);
                }
                s_qm[x] = acc;
                unsigned short us = f2h(acc);
                int pi = __shfl_xor((int)us, 1);
                if ((x & 1) == 0) s_qmh[x >> 1] = (uint32)us | ((uint32)pi << 16);
            }
        }
        // Per-step store-queue drain on otherwise-idle waves.
        asm volatile("s_waitcnt vmcnt(0)" ::: "memory");
        bar();
    }

    // Epilogue: qc for t = NT-1, then store qm/qc (coalesced)
    if (tid >= 256 && tid < 784) {
        const int i = iT, l = lT;
        float t_il = 0.f, t_li = 0.f;
        #pragma unroll
        for (int q = 0; q < NA; q++) {
            t_il = fmaf(s_Y[q * NX + i], s_T1[q * NXP + l], t_il);
            t_li = fmaf(s_Y[q * NX + l], s_T1[q * NXP + i], t_li);
        }
        if (i == l) {
            s_qc[i * NXP + i] = s_pc[i * NXP + i] - t_il + EPSV;
        } else {
            float v = 0.5f * ((s_pc[i * NXP + l] - t_il) + (s_pc[l * NXP + i] - t_li));
            s_qc[i * NXP + l] = v;
            s_qc[l * NXP + i] = v;
        }
    }
    bar();
    {
        const size_t mLast = (size_t)(NT - 1) * NB + b;
        for (int s = tid; s < NX + NX * NX; s += 1024) {
            if (s < NX)
                __builtin_nontemporal_store(s_qm[s], out + qmO + mLast * NX + s);
            else {
                int o = s - NX, i = o >> 5, l = o & 31;
                __builtin_nontemporal_store(s_qc[i * NXP + l],
                                            out + qcO + mLast * NX * NX + o);
            }
        }
    }
}

// ---------------------------------------------------------------------------
extern "C" void kernel_launch(void* const* d_in, const int* in_sizes, int n_in,
                              void* d_out, int out_size, void* d_ws, size_t ws_size,
                              hipStream_t stream)
{
    const float* u    = (const float*)d_in[0];
    const float* a    = (const float*)d_in[1];
    const float* W1   = (const float*)d_in[2];
    const float* b1   = (const float*)d_in[3];
    const float* W2   = (const float*)d_in[4];
    const float* b2   = (const float*)d_in[5];
    const float* WA   = (const float*)d_in[6];
    const float* bA   = (const float*)d_in[7];
    const float* WB   = (const float*)d_in[8];
    const float* bB   = (const float*)d_in[9];
    const float* WC   = (const float*)d_in[10];
    const float* bC   = (const float*)d_in[11];
    const float* Wnx  = (const float*)d_in[12];
    const float* bnx  = (const float*)d_in[13];
    const float* Wna  = (const float*)d_in[14];
    const float* bna  = (const float*)d_in[15];
    const float* alph = (const float*)d_in[16];

    uint32* wsu = (uint32*)d_ws;
    float* out = (float*)d_out;

    auto pk = [&](const float* src, int O, int K, size_t dst_off, int LDP, int off) {
        int n = O * (K / 2);
        pack_half_off<<<(n + 255) / 256, 256, 0, stream>>>(src, wsu + dst_off, O, K, LDP, off);
    };
    pk(W1,  NH,      NX, OFF_W1, NH,  0);
    pk(W2,  NH,      NH, OFF_W2, NH,  0);
    pk(WA,  NX * NX, NH, OFF_H1, H1P, 0);
    pk(WB,  NX * NU, NH, OFF_H1, H1P, NX * NX);
    pk(Wnx, NX,      NH, OFF_H1, H1P, NX * NX + NX * NU);
    pk(WC,  NA * NX, NH, OFF_H2, H2P, 0);
    pk(Wna, NA,      NH, OFF_H2, H2P, NA * NX);

    pack_bias3<<<(H1O + 255) / 256, 256, 0, stream>>>(bA, NX * NX, bB, NX * NU, bnx, NX,
                                                      (float*)(wsu + OFF_B1));
    pack_bias3<<<(H2O + 255) / 256, 256, 0, stream>>>(bC, NA * NX, bna, NA, nullptr, 0,
                                                      (float*)(wsu + OFF_B2));

    kf_kernel<<<NB, 1024, 0, stream>>>(u, a, wsu, b1, b2, alph, out);
}